// Round 9
// baseline (1593.072 us; speedup 1.0000x reference)
//
#include <hip/hip_runtime.h>
#include <hip/hip_fp16.h>
#include <cstdint>
#include <cstddef>

#define SEQ   128
#define BATCH 256
#define HDIM  1024
#define ODIM  128
#define NBLK  256

typedef _Float16 half_t;
typedef _Float16 half8 __attribute__((ext_vector_type(8)));
typedef float    f32x4 __attribute__((ext_vector_type(4)));
typedef unsigned long long u64;

// dynamic LDS layout (extern __shared__ + hipFuncSetAttribute):
//   Bs (gates g,o weights, f16)  at      0 .. 131072   (128 KB)
//   P  (2-phase K-reduce, fp32)  at 131072 .. 155648   (24 KB)
//   Hs (h staging, f16)          at 155648 .. 157696   (2 KB)
//   icomm                        at 157696 .. 157760
#define LDS_P_OFF    131072
#define LDS_HS_OFF   155648
#define LDS_IC_OFF   157696
#define LDS_BYTES    157760          // < 160 KiB

// ws: 129 fresh h buffers; then flagsA (L2-local), flagsB (LLC), flags0, cnt
#define HBUF_BYTES   524288
#define FLAGSA_OFF   ((size_t)129 * HBUF_BYTES)      // 67,633,152
#define FLAGSB_OFF   (FLAGSA_OFF + 131072)
#define FLAGS0_OFF   (FLAGSB_OFF + 131072)
#define CNT_OFF      (FLAGS0_OFF + 1024)
#define INIT_INTS    ((131072 + 131072 + 1024 + 32) / 4)

__device__ __forceinline__ float sigmoidf_(float z) {
    return 1.0f / (1.0f + __expf(-z));
}
__device__ __forceinline__ float tanhf_(float z) {
    z = fminf(fmaxf(z, -30.0f), 30.0f);
    float e = __expf(2.0f * z);
    return (e - 1.0f) / (e + 1.0f);
}
// L1-bypass load (hits the XCD-local L2): fast-mode flag polling.
__device__ __forceinline__ int flag_ld_sc0(const int* p) {
    int v;
    asm volatile("global_load_dword %0, %1, off sc0\n\ts_waitcnt vmcnt(0)"
                 : "=v"(v) : "v"(p) : "memory");
    return v;
}

// Zero flag/cnt region (ws re-poisoned to 0xAA before every timed call).
__global__ __launch_bounds__(256) void lstm_init(int* __restrict__ z) {
    const int i = blockIdx.x * 256 + threadIdx.x;
    if (i < INIT_INTS) z[i] = 0;
}

// ---------------------------------------------------------------------------
// Persistent LSTM. 256 blocks x 256 threads, 1 block/CU (154 KB LDS).
// Group of 32 blocks owns 32 batch rows; block slot s owns 32 hidden units
// x 4 gates; wave = K-quarter. Weights: gates f,i in 128 VGPRs/lane,
// gates g,o in 128 KB LDS (conflict-free layout). Spill-free (~290 regs).
// Fast mode (each XCD hosts exactly 32 blocks, discovered via XCC_ID +
// ticket): group = XCD; h AND flags stay in the XCD-local L2 (normal
// stores; sc0 L1-bypass polls; fresh h buffer per step => no stale L1/L2
// copies; lstm_init's zeros reach LLC at its dispatch end, refills share
// the producer's L2). Producers dual-write flags (L2-local + sc1 LLC);
// a sticky 1024-sweep watchdog drops a block to the R5-proven LLC protocol
// => broken sc0 degrades to slow-but-correct, never a hang. Fallback mode
// (unbalanced placement): full R5 protocol (sc1 h stores + LLC polls).
// ---------------------------------------------------------------------------
__global__ __launch_bounds__(256, 1) void lstm_persist(
    const float* __restrict__ x,
    const float* __restrict__ Wfh, const float* __restrict__ Wih,
    const float* __restrict__ Wgh, const float* __restrict__ Woh,
    const float* __restrict__ Wfx, const float* __restrict__ Wix,
    const float* __restrict__ Wgx, const float* __restrict__ Wox,
    const float* __restrict__ bfx, const float* __restrict__ bix,
    const float* __restrict__ bgx, const float* __restrict__ box,
    const float* __restrict__ bfh, const float* __restrict__ bih,
    const float* __restrict__ bgh, const float* __restrict__ boh,
    const float* __restrict__ Wph, const float* __restrict__ bph,
    char* __restrict__ wsbase, float* __restrict__ out)
{
    extern __shared__ char smem[];
    half_t* Bs    = (half_t*)smem;
    float*  P     = (float*)(smem + LDS_P_OFF);
    half_t* Hs    = (half_t*)(smem + LDS_HS_OFF);
    int*    icomm = (int*)(smem + LDS_IC_OFF);

    int* flagsA = (int*)(wsbase + FLAGSA_OFF);
    int* flagsB = (int*)(wsbase + FLAGSB_OFF);
    int* flags0 = (int*)(wsbase + FLAGS0_OFF);
    int* cnt    = (int*)(wsbase + CNT_OFF);

    const int tid  = threadIdx.x;
    const int blk  = blockIdx.x;
    const int w    = tid >> 6;
    const int lane = tid & 63;
    const int l15  = lane & 15;
    const int q    = lane >> 4;

    // ---- phase 0: XCD discovery, ticket, one-time grid barrier, mode ----
    if (tid == 0) {
        int xcd;
        asm volatile("s_getreg_b32 %0, hwreg(HW_REG_XCC_ID)" : "=s"(xcd));
        xcd &= 7;
        const int tk = atomicAdd(&cnt[xcd], 1);
        icomm[0] = xcd;
        icomm[1] = tk;
        __hip_atomic_store(&flags0[blk], 1, __ATOMIC_RELEASE,
                           __HIP_MEMORY_SCOPE_AGENT);
    }
    if (w == 0) {
        for (;;) {
            int ok = 1;
#pragma unroll
            for (int i = 0; i < 4; ++i)
                ok &= (__hip_atomic_load(&flags0[lane * 4 + i], __ATOMIC_RELAXED,
                                         __HIP_MEMORY_SCOPE_AGENT) == 1);
            if (__all(ok)) break;
            __builtin_amdgcn_s_sleep(8);
        }
        const int v = (lane < 8)
            ? __hip_atomic_load(&cnt[lane], __ATOMIC_RELAXED,
                                __HIP_MEMORY_SCOPE_AGENT) : 32;
        icomm[2] = __all(v == 32) ? 1 : 0;
    }
    __syncthreads();
    const int fast  = icomm[2];
    const int group = fast ? icomm[0] : (blk >> 5);
    const int slot  = fast ? icomm[1] : (blk & 31);
    const int m0    = group << 5;          // 32 batch rows
    const int ubase = slot << 5;           // 32 hidden units (x4 gates)
    const int k0    = w << 8;              // wave's K-quarter

    // ---- phase 1a: gates f,i fp32 -> f16 into registers ----
    // tile j (0..3): gate g=j>>1, unit-half j&1, rows ubase+(j&1)*16+l15;
    // frag (j,kk) = W[row][k0 + kk*32 + q*8 .. +8]
    half8 Breg[4][8];
    {
        const float* Wg[2] = {Wfh, Wih};
#pragma unroll
        for (int j = 0; j < 4; ++j) {
            const float* wr = Wg[j >> 1]
                + (size_t)(ubase + ((j & 1) << 4) + l15) * HDIM + k0 + (q << 3);
#pragma unroll
            for (int kk = 0; kk < 8; ++kk) {
                const float4 v0 = *(const float4*)(wr + kk * 32);
                const float4 v1 = *(const float4*)(wr + kk * 32 + 4);
                half8 hv;
                hv[0] = (half_t)v0.x; hv[1] = (half_t)v0.y;
                hv[2] = (half_t)v0.z; hv[3] = (half_t)v0.w;
                hv[4] = (half_t)v1.x; hv[5] = (half_t)v1.y;
                hv[6] = (half_t)v1.z; hv[7] = (half_t)v1.w;
                Breg[j][kk] = hv;
            }
        }
    }
    // ---- phase 1b: gates g,o -> LDS ----
    // d = (((w8*8+kk)*4+jl)*4+q)*16+l ; jl: gate=jl>>1 (0=g,1=o), half=jl&1.
    // K-loop read addr per (w,kk,jl) is contiguous 1024 B -> conflict-free.
    for (int d = tid; d < 8192; d += 256) {
        const int l = d & 15, qq = (d >> 4) & 3, jl = (d >> 6) & 3;
        const int kk = (d >> 8) & 7, w8 = d >> 11;
        const float* src = ((jl >> 1) ? Woh : Wgh)
            + (size_t)(ubase + ((jl & 1) << 4) + l) * HDIM
            + (w8 << 8) + (kk << 5) + (qq << 3);
        const float4 v0 = *(const float4*)src;
        const float4 v1 = *(const float4*)(src + 4);
        half8 hv;
        hv[0] = (half_t)v0.x; hv[1] = (half_t)v0.y;
        hv[2] = (half_t)v0.z; hv[3] = (half_t)v0.w;
        hv[4] = (half_t)v1.x; hv[5] = (half_t)v1.y;
        hv[6] = (half_t)v1.z; hv[7] = (half_t)v1.w;
        *(half8*)(Bs + (size_t)d * 8) = hv;
    }

    // ---- epilogue constants: wave owns (mt_w = w>>1, p_w = w&1) ----
    const int mt_w = w >> 1, p_w = w & 1;
    const int u_e  = ubase + (p_w << 4) + l15;
    const float bf = bfx[u_e] + bfh[u_e], bi = bix[u_e] + bih[u_e];
    const float bg = bgx[u_e] + bgh[u_e], bo = box[u_e] + boh[u_e];
    const float wf = Wfx[u_e], wi = Wix[u_e], wg = Wgx[u_e], wo = Wox[u_e];
    f32x4 creg = {0.f, 0.f, 0.f, 0.f};
    int useLLC = 0;   // sticky per-block watchdog state (held by wave 0)

    __syncthreads();   // Bs ready

    for (int t = 0; t < SEQ; ++t) {
        const half_t* hin  = (const half_t*)(wsbase + (size_t)t * HBUF_BYTES);
        half_t*       hout = (half_t*)(wsbase + (size_t)(t + 1) * HBUF_BYTES);

        // x prefetch for this wave's owned rows
        const float4 xv = *(const float4*)&x[t * BATCH + m0 + (mt_w << 4) + (q << 2)];

        f32x4 acc[2][8] = {};
        if (t > 0) {
            const half_t* abase = hin + (size_t)(m0 + l15) * HDIM + k0 + (q << 3);
            half8 a0[8], a1[8];
#pragma unroll
            for (int kk = 0; kk < 8; ++kk) {
                a0[kk] = *(const half8*)(abase + kk * 32);
                a1[kk] = *(const half8*)(abase + 16 * HDIM + kk * 32);
            }
#pragma unroll
            for (int kk = 0; kk < 8; ++kk) {
#pragma unroll
                for (int j = 0; j < 4; ++j) {
                    acc[0][j] = __builtin_amdgcn_mfma_f32_16x16x32_f16(
                        a0[kk], Breg[j][kk], acc[0][j], 0, 0, 0);
                    acc[1][j] = __builtin_amdgcn_mfma_f32_16x16x32_f16(
                        a1[kk], Breg[j][kk], acc[1][j], 0, 0, 0);
                }
#pragma unroll
                for (int jl = 0; jl < 4; ++jl) {
                    const half8 bb = *(const half8*)(Bs +
                        ((size_t)((((w << 3) + kk) << 2) + jl) << 9)
                        + (((q << 4) + l15) << 3));
                    acc[0][4 + jl] = __builtin_amdgcn_mfma_f32_16x16x32_f16(
                        a0[kk], bb, acc[0][4 + jl], 0, 0, 0);
                    acc[1][4 + jl] = __builtin_amdgcn_mfma_f32_16x16x32_f16(
                        a1[kk], bb, acc[1][4 + jl], 0, 0, 0);
                }
            }
        }

        // ---- 2-phase cross-wave K-reduce via 24 KB P + fused epilogue ----
        // tile (ph, j) owned by wave (ph*2 + (j&1)); writers compact to 3 slots
#pragma unroll
        for (int ph = 0; ph < 2; ++ph) {
            if (ph == 1) __syncthreads();     // ph0 reads done before ph1 writes
#pragma unroll
            for (int j = 0; j < 8; ++j) {
                const int ow = (ph << 1) | (j & 1);
                if (w != ow) {
                    const int s = w - (w > ow ? 1 : 0);
                    *(f32x4*)&P[(j * 3 + s) * 256 + (lane << 2)] = acc[ph][j];
                }
            }
            __syncthreads();                  // partials visible
            if (mt_w == ph) {
                f32x4 z[4];
#pragma unroll
                for (int g = 0; g < 4; ++g) {
                    const int j = (g << 1) | p_w;
                    f32x4 s = acc[ph][j];
#pragma unroll
                    for (int src = 0; src < 3; ++src)
                        s += *(const f32x4*)&P[(j * 3 + src) * 256 + (lane << 2)];
                    z[g] = s;
                }
                const int lr0 = (ph << 4) + (q << 2);
#pragma unroll
                for (int e = 0; e < 4; ++e) {
                    const float xe = (e == 0) ? xv.x : (e == 1) ? xv.y
                                   : (e == 2) ? xv.z : xv.w;
                    const float fg = sigmoidf_(z[0][e] + xe * wf + bf);
                    const float ig = sigmoidf_(z[1][e] + xe * wi + bi);
                    const float gg = tanhf_  (z[2][e] + xe * wg + bg);
                    const float og = sigmoidf_(z[3][e] + xe * wo + bo);
                    const float cn = gg * ig + creg[e] * fg;
                    creg[e] = cn;
                    Hs[(lr0 + e) * 32 + (p_w << 4) + l15] = (half_t)(tanhf_(cn) * og);
                }
            }
        }
        __syncthreads();   // Hs complete

        // ---- coalesced h store: 1 u64/thread ----
        {
            const int r = tid >> 3, ch = tid & 7;
            const u64 v = *(const u64*)&Hs[r * 32 + ch * 4];
            u64* dst = (u64*)(hout + (size_t)(m0 + r) * HDIM + ubase + ch * 4);
            if (fast) *dst = v;   // normal store -> XCD-local L2 (L1 is WT)
            else __hip_atomic_store(dst, v, __ATOMIC_RELAXED,
                                    __HIP_MEMORY_SCOPE_AGENT);
        }
        asm volatile("s_waitcnt vmcnt(0)" ::: "memory");
        __syncthreads();   // all waves' h visible in (at least) this XCD's L2

        // ---- dual flag store + poll (sc0 local fast path, LLC fallback) ----
        int* flA = &flagsA[(t << 8) + (group << 5)];
        int* flB = &flagsB[(t << 8) + (group << 5)];
        if (tid == 0) {
            if (fast) flA[slot] = 1;          // XCD-local (dirty in this L2)
            __hip_atomic_store(&flB[slot], 1, __ATOMIC_RELAXED,
                               __HIP_MEMORY_SCOPE_AGENT);
        }
        if (w == 0) {
            int done = 0;
            if (fast && !useLLC) {
                int sweeps = 0;
                for (;;) {
                    const int v = flag_ld_sc0(&flA[lane & 31]);
                    if (__all(v == 1)) { done = 1; break; }
                    if (++sweeps > 1024) { useLLC = 1; break; }  // watchdog
                    __builtin_amdgcn_s_sleep(1);
                }
            }
            if (!done) {
                const int* pf = &flB[lane & 31];
                for (;;) {
                    const int v = __hip_atomic_load(pf, __ATOMIC_RELAXED,
                                                    __HIP_MEMORY_SCOPE_AGENT);
                    if (__all(v == 1)) break;
                    __builtin_amdgcn_s_sleep(1);
                }
            }
        }
        asm volatile("" ::: "memory");
        __syncthreads();
    }

    // ---- fused projection + softmax: block -> batch row ----
    const int row = (group << 5) + slot;
    float* sm     = (float*)(smem + LDS_P_OFF);   // reuse P region (6 KB)
    float* hrow   = sm;
    float* psum   = sm + 1024;
    float* logits = sm + 1280;
    const half_t* hf = (const half_t*)(wsbase + (size_t)SEQ * HBUF_BYTES)
                     + ((size_t)row << 10);

    for (int k = tid; k < HDIM; k += 256) hrow[k] = (float)hf[k];
    __syncthreads();

    const int j = tid & 127, hlf = tid >> 7;
    const float4* wp = (const float4*)(Wph + (size_t)j * HDIM + hlf * 512);
    const float4* hp = (const float4*)(hrow + hlf * 512);
    float s = 0.0f;
#pragma unroll 8
    for (int k4 = 0; k4 < 128; ++k4) {
        const float4 wv = wp[k4];
        const float4 hv = hp[k4];
        s += wv.x * hv.x + wv.y * hv.y + wv.z * hv.z + wv.w * hv.w;
    }
    psum[tid] = s;
    __syncthreads();
    if (tid < ODIM) logits[tid] = psum[tid] + psum[tid + 128] + bph[tid];
    __syncthreads();
    if (tid < ODIM) {
        float mx = -1e30f;
        for (int i = 0; i < ODIM; ++i) mx = fmaxf(mx, logits[i]);
        psum[tid] = __expf(logits[tid] - mx);
    }
    __syncthreads();
    if (tid < ODIM) {
        float ssum = 0.0f;
        for (int i = 0; i < ODIM; ++i) ssum += psum[i];
        out[row * ODIM + tid] = psum[tid] / ssum;
    }
}

// ---------------------------------------------------------------------------
extern "C" void kernel_launch(void* const* d_in, const int* in_sizes, int n_in,
                              void* d_out, int out_size, void* d_ws, size_t ws_size,
                              hipStream_t stream) {
    const float* x   = (const float*)d_in[0];
    const float* Wfx = (const float*)d_in[1];
    const float* bfx = (const float*)d_in[2];
    const float* Wfh = (const float*)d_in[3];
    const float* bfh = (const float*)d_in[4];
    const float* Wix = (const float*)d_in[5];
    const float* bix = (const float*)d_in[6];
    const float* Wih = (const float*)d_in[7];
    const float* bih = (const float*)d_in[8];
    const float* Wgx = (const float*)d_in[9];
    const float* bgx = (const float*)d_in[10];
    const float* Wgh = (const float*)d_in[11];
    const float* bgh = (const float*)d_in[12];
    const float* Wox = (const float*)d_in[13];
    const float* box = (const float*)d_in[14];
    const float* Woh = (const float*)d_in[15];
    const float* boh = (const float*)d_in[16];
    const float* Wph = (const float*)d_in[17];
    const float* bph = (const float*)d_in[18];
    float* outp = (float*)d_out;

    char* ws = (char*)d_ws;
    int* zbase = (int*)(ws + FLAGSA_OFF);

    lstm_init<<<(INIT_INTS + 255) / 256, 256, 0, stream>>>(zbase);

    (void)hipFuncSetAttribute((const void*)lstm_persist,
                              hipFuncAttributeMaxDynamicSharedMemorySize,
                              LDS_BYTES);

    void* args[] = {
        (void*)&x,
        (void*)&Wfh, (void*)&Wih, (void*)&Wgh, (void*)&Woh,
        (void*)&Wfx, (void*)&Wix, (void*)&Wgx, (void*)&Wox,
        (void*)&bfx, (void*)&bix, (void*)&bgx, (void*)&box,
        (void*)&bfh, (void*)&bih, (void*)&bgh, (void*)&boh,
        (void*)&Wph, (void*)&bph,
        (void*)&ws, (void*)&outp
    };
    hipError_t lerr = hipLaunchCooperativeKernel((const void*)lstm_persist,
                                                 dim3(NBLK), dim3(256),
                                                 args, LDS_BYTES, stream);
    if (lerr != hipSuccess) {
        // co-residency is structurally forced (154 KB LDS -> 1 block/CU,
        // 256 blocks on 256 CUs); the coop API was only validation.
        lstm_persist<<<dim3(NBLK), dim3(256), LDS_BYTES, stream>>>(
            x, Wfh, Wih, Wgh, Woh, Wfx, Wix, Wgx, Wox,
            bfx, bix, bgx, box, bfh, bih, bgh, boh,
            Wph, bph, ws, outp);
    }
}